// Round 15
// baseline (190.643 us; speedup 1.0000x reference)
//
#include <hip/hip_runtime.h>
#include <hip/hip_bf16.h>

#define B_DIM 16
#define KQ    2048
#define W_DIM 2048
#define D_DIM 128
#define QBLK  64
#define KVB   32
#define NT    (W_DIM / KVB)   // 64
#define TILEU 12288           // u16 per ws tile: K 16 frags + V 8 frags, 1KB each

typedef float f4 __attribute__((ext_vector_type(4)));
typedef float f32x16 __attribute__((ext_vector_type(16)));
typedef __bf16 bf16x8 __attribute__((ext_vector_type(8)));
typedef unsigned short u16x4 __attribute__((ext_vector_type(4)));
typedef unsigned short u16x8 __attribute__((ext_vector_type(8)));

static __device__ __forceinline__ unsigned short f2bf(float x) {
  __bf16 h = (__bf16)x;
  return __builtin_bit_cast(unsigned short, h);
}

// ws tile layout per (b,t): 24 fragment chunks of 1KB, each the EXACT register
// image of one MFMA operand fragment for a 64-lane wave (lane l owns 16B at
// chunk + l*16):
//   K frags [u16 0,8192):    ch = s*8+st; lane l=(hi,ln): K_s[k=ln][d=st*16+hi*8..+8]
//   V frags [u16 8192,12288): ch = db*2+ks; lane l: slot j = V[k=16ks+4hi+(j&3)+8(j>>2)][d=db*32+ln]
__global__ __launch_bounds__(256, 2)
void prepass(const float* __restrict__ K1g, const float* __restrict__ K2g,
             const float* __restrict__ Vg, unsigned short* __restrict__ ws)
{
  __shared__ unsigned short lv[KVB][132];
  const int tid = threadIdx.x;
  const int bt  = blockIdx.x;               // b*NT + t
  const size_t gsrc = (size_t)bt * KVB * D_DIM;
  unsigned short* wt = ws + (size_t)bt * TILEU;

  // ---- K fragments: 16 chunks x 64 lanes ----
#pragma unroll
  for (int uu = 0; uu < 4; ++uu) {
    const int unit = uu * 256 + tid;
    const int ch = unit >> 6, l = unit & 63;
    const int sK = ch >> 3, st = ch & 7;
    const int h2 = l >> 5, l2 = l & 31;
    const float* src = (sK ? K2g : K1g) + gsrc + l2 * D_DIM + st * 16 + h2 * 8;
    f4 a0 = *(const f4*)src, a1 = *(const f4*)(src + 4);
    u16x8 o1 = { f2bf(a0[0]), f2bf(a0[1]), f2bf(a0[2]), f2bf(a0[3]),
                 f2bf(a1[0]), f2bf(a1[1]), f2bf(a1[2]), f2bf(a1[3]) };
    *(u16x8*)(wt + unit * 8) = o1;
  }

  // ---- V: stage bf16 tile ----
#pragma unroll
  for (int uu = 0; uu < 4; ++uu) {
    const int fi = uu * 256 + tid;
    const int k = fi >> 5, d4 = (fi & 31) * 4;
    f4 v = *(const f4*)(Vg + gsrc + k * D_DIM + d4);
    *(u16x4*)&lv[k][d4] = (u16x4){ f2bf(v[0]), f2bf(v[1]), f2bf(v[2]), f2bf(v[3]) };
  }
  __syncthreads();

  // ---- V fragments: 8 chunks x 64 lanes ----
#pragma unroll
  for (int uu = 0; uu < 2; ++uu) {
    const int unit = uu * 256 + tid;
    const int ch = unit >> 6, l = unit & 63;
    const int ks = ch & 1, db = ch >> 1;
    const int h2 = l >> 5, l2 = l & 31;
    const int d  = db * 32 + l2;
    u16x8 ov;
#pragma unroll
    for (int j = 0; j < 8; ++j) {
      const int k = 16 * ks + 4 * h2 + (j & 3) + 8 * (j >> 2);
      ov[j] = lv[k][d];
    }
    *(u16x8*)(wt + 8192 + unit * 8) = ov;
  }
}

// ---------------- main: zero-barrier loop + register double-buffer prefetch ----------------
// Unrolled x2 with NAMED K-fragment sets (kfA/kfB): body(t) issues next tile's
// K loads into the idle set (full-body slack ~900cy), V loads at body top
// (~300cy ahead of PV use). No LDS/barriers in loop; waves drift freely.
__global__ __launch_bounds__(256, 2)
void diffattn(const float* __restrict__ Q1g, const float* __restrict__ Q2g,
              const unsigned short* __restrict__ ws,
              const float* __restrict__ lamp, float* __restrict__ Og)
{
  __shared__ char smem[32768];   // epilogue combine only

  const int tid  = threadIdx.x;
  const int wv   = tid >> 6;     // 0..3
  const int lane = tid & 63;
  const int hi   = lane >> 5;
  const int ln   = lane & 31;
  const int s    = wv & 1;       // stream
  const int qh   = wv >> 1;      // q chunk (32 rows)

  // XCD-aware bijective swizzle: 512 = 8 XCDs x 64
  const int wg  = blockIdx.x;
  const int swz = (wg & 7) * 64 + (wg >> 3);
  const int qt  = swz & 31;
  const int b   = swz >> 5;
  const int q0  = qt * QBLK;

  const float qscale = 0.08838834764831845f * 1.4426950408889634f; // 1/sqrt(128)*log2(e)

  // ---- Q fragments (B-operand): lane = q-col ln, d-slots hi*8+j+16*step
  const float* Qs = s ? Q2g : Q1g;
  bf16x8 qf[8];
  {
    const float* qp = Qs + ((size_t)b * KQ + q0 + qh * 32 + ln) * D_DIM + hi * 8;
#pragma unroll
    for (int st = 0; st < 8; ++st) {
      f4 lo = *(const f4*)(qp + st * 16);
      f4 h4 = *(const f4*)(qp + st * 16 + 4);
      bf16x8 tq;
#pragma unroll
      for (int j = 0; j < 4; ++j) {
        tq[j]     = (__bf16)(lo[j] * qscale);
        tq[4 + j] = (__bf16)(h4[j] * qscale);
      }
      qf[st] = tq;
    }
  }

  f32x16 o[4];
#pragma unroll
  for (int db = 0; db < 4; ++db)
#pragma unroll
    for (int i = 0; i < 16; ++i) o[db][i] = 0.f;

  float lsp[2] = {0.f, 0.f};

  const unsigned short* wsb = ws + (size_t)b * NT * TILEU;
  const unsigned short* kfp = wsb + (size_t)(s * 8) * 512 + lane * 8;
  const unsigned short* vfp = wsb + 8192 + lane * 8;

  bf16x8 kfA[8], kfB[8];

#define LOADK(dst, tt)                                              \
  {                                                                 \
    const size_t _o = (size_t)(tt) * TILEU;                         \
    _Pragma("unroll")                                               \
    for (int st = 0; st < 8; ++st)                                  \
      dst[st] = *(const bf16x8*)(kfp + _o + st * 512);              \
  }

#define BODY(kfc, kfn, tt)                                          \
  {                                                                 \
    const int tn = ((tt) + 2 < NT) ? (tt) + 2 : NT - 1;             \
    LOADK(kfn, (tt) + 1);                                           \
    (void)tn;                                                       \
    bf16x8 vf[8];                                                   \
    {                                                               \
      const size_t _o = (size_t)(tt) * TILEU;                       \
      _Pragma("unroll")                                             \
      for (int ch = 0; ch < 8; ++ch)                                \
        vf[ch] = *(const bf16x8*)(vfp + _o + ch * 512);             \
    }                                                               \
    f32x16 s0, s1;                                                  \
    _Pragma("unroll")                                               \
    for (int i = 0; i < 16; ++i) { s0[i] = 0.f; s1[i] = 0.f; }      \
    __builtin_amdgcn_s_setprio(1);                                  \
    _Pragma("unroll")                                               \
    for (int st = 0; st < 4; ++st) {                                \
      s0 = __builtin_amdgcn_mfma_f32_32x32x16_bf16(kfc[st],     qf[st],     s0, 0, 0, 0); \
      s1 = __builtin_amdgcn_mfma_f32_32x32x16_bf16(kfc[st + 4], qf[st + 4], s1, 0, 0, 0); \
    }                                                               \
    __builtin_amdgcn_s_setprio(0);                                  \
    bf16x8 pa0, pa1;                                                \
    _Pragma("unroll")                                               \
    for (int j = 0; j < 8; ++j) {                                   \
      const float p0 = __builtin_amdgcn_exp2f(s0[j] + s1[j]);       \
      const float p1 = __builtin_amdgcn_exp2f(s0[8 + j] + s1[8 + j]); \
      lsp[0] += p0; lsp[1] += p1;                                   \
      pa0[j] = (__bf16)p0; pa1[j] = (__bf16)p1;                     \
    }                                                               \
    __builtin_amdgcn_s_setprio(1);                                  \
    _Pragma("unroll")                                               \
    for (int db = 0; db < 4; ++db) {                                \
      o[db] = __builtin_amdgcn_mfma_f32_32x32x16_bf16(pa0, vf[db * 2],     o[db], 0, 0, 0); \
      o[db] = __builtin_amdgcn_mfma_f32_32x32x16_bf16(pa1, vf[db * 2 + 1], o[db], 0, 0, 0); \
    }                                                               \
    __builtin_amdgcn_s_setprio(0);                                  \
  }

  LOADK(kfA, 0);

#pragma unroll 1
  for (int t = 0; t < NT; t += 2) {
    // body 1: compute tile t with kfA, prefetch K(t+1) -> kfB
    BODY(kfA, kfB, t);
    // body 2: compute tile t+1 with kfB, prefetch K(t+2, clamped) -> kfA
    {
      const int t1 = t + 1;
      const int t2 = (t + 2 < NT) ? t + 2 : NT - 1;
      LOADK(kfA, t2);
      bf16x8 vf[8];
      {
        const size_t _o = (size_t)t1 * TILEU;
#pragma unroll
        for (int ch = 0; ch < 8; ++ch)
          vf[ch] = *(const bf16x8*)(vfp + _o + ch * 512);
      }
      f32x16 s0, s1;
#pragma unroll
      for (int i = 0; i < 16; ++i) { s0[i] = 0.f; s1[i] = 0.f; }
      __builtin_amdgcn_s_setprio(1);
#pragma unroll
      for (int st = 0; st < 4; ++st) {
        s0 = __builtin_amdgcn_mfma_f32_32x32x16_bf16(kfB[st],     qf[st],     s0, 0, 0, 0);
        s1 = __builtin_amdgcn_mfma_f32_32x32x16_bf16(kfB[st + 4], qf[st + 4], s1, 0, 0, 0);
      }
      __builtin_amdgcn_s_setprio(0);
      bf16x8 pa0, pa1;
#pragma unroll
      for (int j = 0; j < 8; ++j) {
        const float p0 = __builtin_amdgcn_exp2f(s0[j] + s1[j]);
        const float p1 = __builtin_amdgcn_exp2f(s0[8 + j] + s1[8 + j]);
        lsp[0] += p0; lsp[1] += p1;
        pa0[j] = (__bf16)p0; pa1[j] = (__bf16)p1;
      }
      __builtin_amdgcn_s_setprio(1);
#pragma unroll
      for (int db = 0; db < 4; ++db) {
        o[db] = __builtin_amdgcn_mfma_f32_32x32x16_bf16(pa0, vf[db * 2],     o[db], 0, 0, 0);
        o[db] = __builtin_amdgcn_mfma_f32_32x32x16_bf16(pa1, vf[db * 2 + 1], o[db], 0, 0, 0);
      }
      __builtin_amdgcn_s_setprio(0);
    }
  }

  // ---- epilogue: reduce l, combine streams via LDS ----
  const float lam = 1.f / (1.f + __expf(-lamp[0]));
  float ls = lsp[0] + lsp[1];
  const float lt  = ls + __shfl_xor(ls, 32);
  const float fac = s ? lam : 1.f;
  float wq[16];
#pragma unroll
  for (int r = 0; r < 16; ++r)
    wq[r] = fac / __shfl(lt, (r & 3) + 8 * (r >> 2) + 4 * hi);

  if (s == 1) {
#pragma unroll
    for (int db = 0; db < 4; ++db)
#pragma unroll
      for (int r = 0; r < 16; ++r) {
        const int q = qh * 32 + (r & 3) + 8 * (r >> 2) + 4 * hi;
        *(float*)(smem + q * 512 + (db * 32 + ln) * 4) = o[db][r] * wq[r];
      }
  }
  __syncthreads();
  if (s == 0) {
    float* op = Og + ((size_t)b * KQ + q0) * D_DIM;
#pragma unroll
    for (int db = 0; db < 4; ++db)
#pragma unroll
      for (int r = 0; r < 16; ++r) {
        const int q = qh * 32 + (r & 3) + 8 * (r >> 2) + 4 * hi;
        const float o2v = *(const float*)(smem + q * 512 + (db * 32 + ln) * 4);
        op[q * D_DIM + db * 32 + ln] = o[db][r] * wq[r] - o2v;
      }
  }
}

extern "C" void kernel_launch(void* const* d_in, const int* in_sizes, int n_in,
                              void* d_out, int out_size, void* d_ws, size_t ws_size,
                              hipStream_t stream) {
  const float* Q1 = (const float*)d_in[0];
  const float* Q2 = (const float*)d_in[1];
  const float* K1 = (const float*)d_in[2];
  const float* K2 = (const float*)d_in[3];
  const float* V  = (const float*)d_in[4];
  const float* lm = (const float*)d_in[5];
  float* O = (float*)d_out;

  unsigned short* wsp = (unsigned short*)d_ws;   // 24 MB

  prepass<<<dim3(B_DIM * NT), dim3(256), 0, stream>>>(K1, K2, V, wsp);
  diffattn<<<dim3(B_DIM * (KQ / QBLK)), dim3(256), 0, stream>>>(Q1, Q2, wsp, lm, O);
}

// Round 16
// 101.680 us; speedup vs baseline: 1.8749x; 1.8749x over previous
//
#include <hip/hip_runtime.h>
#include <hip/hip_bf16.h>

#define B_DIM 16
#define KQ    2048
#define W_DIM 2048
#define D_DIM 128
#define QBLK  64
#define KVB   32
#define NT    (W_DIM / KVB)   // 64
#define TILEU 12288           // u16 per ws tile: K 16 frags + V 8 frags, 1KB each

typedef float f4 __attribute__((ext_vector_type(4)));
typedef float f32x16 __attribute__((ext_vector_type(16)));
typedef __bf16 bf16x8 __attribute__((ext_vector_type(8)));
typedef unsigned short u16x4 __attribute__((ext_vector_type(4)));
typedef unsigned short u16x8 __attribute__((ext_vector_type(8)));

static __device__ __forceinline__ unsigned short f2bf(float x) {
  __bf16 h = (__bf16)x;
  return __builtin_bit_cast(unsigned short, h);
}

// ws tile layout per (b,t): 24 fragment chunks of 1KB, each the EXACT register
// image of one MFMA operand fragment for a 64-lane wave (lane l owns 16B at
// chunk + l*16):
//   K frags [u16 0,8192):    ch = s*8+st; lane l=(hi,ln): K_s[k=ln][d=st*16+hi*8..+8]
//   V frags [u16 8192,12288): ch = db*2+ks; lane l: slot j = V[k=16ks+4hi+(j&3)+8(j>>2)][d=db*32+ln]
__global__ __launch_bounds__(256, 2)
void prepass(const float* __restrict__ K1g, const float* __restrict__ K2g,
             const float* __restrict__ Vg, unsigned short* __restrict__ ws)
{
  __shared__ unsigned short lv[KVB][132];
  const int tid = threadIdx.x;
  const int bt  = blockIdx.x;               // b*NT + t
  const size_t gsrc = (size_t)bt * KVB * D_DIM;
  unsigned short* wt = ws + (size_t)bt * TILEU;

  // ---- K fragments: 16 chunks x 64 lanes ----
#pragma unroll
  for (int uu = 0; uu < 4; ++uu) {
    const int unit = uu * 256 + tid;
    const int ch = unit >> 6, l = unit & 63;
    const int sK = ch >> 3, st = ch & 7;
    const int h2 = l >> 5, l2 = l & 31;
    const float* src = (sK ? K2g : K1g) + gsrc + l2 * D_DIM + st * 16 + h2 * 8;
    f4 a0 = *(const f4*)src, a1 = *(const f4*)(src + 4);
    u16x8 o1 = { f2bf(a0[0]), f2bf(a0[1]), f2bf(a0[2]), f2bf(a0[3]),
                 f2bf(a1[0]), f2bf(a1[1]), f2bf(a1[2]), f2bf(a1[3]) };
    *(u16x8*)(wt + unit * 8) = o1;
  }

  // ---- V: stage bf16 tile ----
#pragma unroll
  for (int uu = 0; uu < 4; ++uu) {
    const int fi = uu * 256 + tid;
    const int k = fi >> 5, d4 = (fi & 31) * 4;
    f4 v = *(const f4*)(Vg + gsrc + k * D_DIM + d4);
    *(u16x4*)&lv[k][d4] = (u16x4){ f2bf(v[0]), f2bf(v[1]), f2bf(v[2]), f2bf(v[3]) };
  }
  __syncthreads();

  // ---- V fragments: 8 chunks x 64 lanes ----
#pragma unroll
  for (int uu = 0; uu < 2; ++uu) {
    const int unit = uu * 256 + tid;
    const int ch = unit >> 6, l = unit & 63;
    const int ks = ch & 1, db = ch >> 1;
    const int h2 = l >> 5, l2 = l & 31;
    const int d  = db * 32 + l2;
    u16x8 ov;
#pragma unroll
    for (int j = 0; j < 8; ++j) {
      const int k = 16 * ks + 4 * h2 + (j & 3) + 8 * (j >> 2);
      ov[j] = lv[k][d];
    }
    *(u16x8*)(wt + 8192 + unit * 8) = ov;
  }
}

// ---------------- main: zero-barrier loop, issue-point-motion prefetch ----------------
// Single kf buffer, rotated one iteration ahead: QK(t) consumes kf, then
// LOADK(kf, t+1) is issued (WAR on the same regs pins it after the last use);
// the loads retire under exp(t)+PV(t)+vf-issue(t+1) (~700cy slack). vf issued
// at iter top, consumed after QK+exp (~500cy slack). No extra registers.
__global__ __launch_bounds__(256, 2)
void diffattn(const float* __restrict__ Q1g, const float* __restrict__ Q2g,
              const unsigned short* __restrict__ ws,
              const float* __restrict__ lamp, float* __restrict__ Og)
{
  __shared__ char smem[32768];   // epilogue combine only

  const int tid  = threadIdx.x;
  const int wv   = tid >> 6;     // 0..3
  const int lane = tid & 63;
  const int hi   = lane >> 5;
  const int ln   = lane & 31;
  const int s    = wv & 1;       // stream
  const int qh   = wv >> 1;      // q chunk (32 rows)

  // XCD-aware bijective swizzle: 512 = 8 XCDs x 64
  const int wg  = blockIdx.x;
  const int swz = (wg & 7) * 64 + (wg >> 3);
  const int qt  = swz & 31;
  const int b   = swz >> 5;
  const int q0  = qt * QBLK;

  const float qscale = 0.08838834764831845f * 1.4426950408889634f; // 1/sqrt(128)*log2(e)

  // ---- Q fragments (B-operand): lane = q-col ln, d-slots hi*8+j+16*step
  const float* Qs = s ? Q2g : Q1g;
  bf16x8 qf[8];
  {
    const float* qp = Qs + ((size_t)b * KQ + q0 + qh * 32 + ln) * D_DIM + hi * 8;
#pragma unroll
    for (int st = 0; st < 8; ++st) {
      f4 lo = *(const f4*)(qp + st * 16);
      f4 h4 = *(const f4*)(qp + st * 16 + 4);
      bf16x8 tq;
#pragma unroll
      for (int j = 0; j < 4; ++j) {
        tq[j]     = (__bf16)(lo[j] * qscale);
        tq[4 + j] = (__bf16)(h4[j] * qscale);
      }
      qf[st] = tq;
    }
  }

  f32x16 o[4];
#pragma unroll
  for (int db = 0; db < 4; ++db)
#pragma unroll
    for (int i = 0; i < 16; ++i) o[db][i] = 0.f;

  float lsp[2] = {0.f, 0.f};

  const unsigned short* wsb = ws + (size_t)b * NT * TILEU;
  const unsigned short* kfp = wsb + (size_t)(s * 8) * 512 + lane * 8;
  const unsigned short* vfp = wsb + 8192 + lane * 8;

  bf16x8 kf[8];
#pragma unroll
  for (int st = 0; st < 8; ++st)
    kf[st] = *(const bf16x8*)(kfp + st * 512);   // tile 0

#pragma unroll 1
  for (int t = 0; t < NT; ++t) {
    const size_t toff = (size_t)t * TILEU;

    // ---- vf(t): issued now, consumed after QK+exp (~500cy slack) ----
    bf16x8 vf[8];
#pragma unroll
    for (int ch = 0; ch < 8; ++ch)
      vf[ch] = *(const bf16x8*)(vfp + toff + ch * 512);

    // ---- QK(t): consumes kf (loaded one iteration ago) ----
    f32x16 s0, s1;
#pragma unroll
    for (int i = 0; i < 16; ++i) { s0[i] = 0.f; s1[i] = 0.f; }
    __builtin_amdgcn_s_setprio(1);
#pragma unroll
    for (int st = 0; st < 4; ++st) {
      s0 = __builtin_amdgcn_mfma_f32_32x32x16_bf16(kf[st],     qf[st],     s0, 0, 0, 0);
      s1 = __builtin_amdgcn_mfma_f32_32x32x16_bf16(kf[st + 4], qf[st + 4], s1, 0, 0, 0);
    }
    __builtin_amdgcn_s_setprio(0);

    // ---- prefetch kf(t+1) into the SAME registers (WAR pins after QK) ----
    {
      const size_t noff = (size_t)((t + 1 < NT) ? t + 1 : NT - 1) * TILEU;
#pragma unroll
      for (int st = 0; st < 8; ++st)
        kf[st] = *(const bf16x8*)(kfp + noff + st * 512);
    }

    // ---- unnormalized exp2 (raw v_exp_f32); P packed into A-fragments ----
    bf16x8 pa0, pa1;
#pragma unroll
    for (int j = 0; j < 8; ++j) {
      const float p0 = __builtin_amdgcn_exp2f(s0[j] + s1[j]);
      const float p1 = __builtin_amdgcn_exp2f(s0[8 + j] + s1[8 + j]);
      lsp[0] += p0;
      lsp[1] += p1;
      pa0[j] = (__bf16)p0;   // slot j <-> k = 4hi + (j&3) + 8(j>>2)   (ks=0)
      pa1[j] = (__bf16)p1;   //                 +16                    (ks=1)
    }

    // ---- PV: O[q][d] ----
    __builtin_amdgcn_s_setprio(1);
#pragma unroll
    for (int db = 0; db < 4; ++db) {
      o[db] = __builtin_amdgcn_mfma_f32_32x32x16_bf16(pa0, vf[db * 2],     o[db], 0, 0, 0);
      o[db] = __builtin_amdgcn_mfma_f32_32x32x16_bf16(pa1, vf[db * 2 + 1], o[db], 0, 0, 0);
    }
    __builtin_amdgcn_s_setprio(0);
  }

  // ---- epilogue: reduce l, combine streams via LDS ----
  const float lam = 1.f / (1.f + __expf(-lamp[0]));
  float ls = lsp[0] + lsp[1];
  const float lt  = ls + __shfl_xor(ls, 32);
  const float fac = s ? lam : 1.f;
  float wq[16];
#pragma unroll
  for (int r = 0; r < 16; ++r)
    wq[r] = fac / __shfl(lt, (r & 3) + 8 * (r >> 2) + 4 * hi);

  if (s == 1) {
#pragma unroll
    for (int db = 0; db < 4; ++db)
#pragma unroll
      for (int r = 0; r < 16; ++r) {
        const int q = qh * 32 + (r & 3) + 8 * (r >> 2) + 4 * hi;
        *(float*)(smem + q * 512 + (db * 32 + ln) * 4) = o[db][r] * wq[r];
      }
  }
  __syncthreads();
  if (s == 0) {
    float* op = Og + ((size_t)b * KQ + q0) * D_DIM;
#pragma unroll
    for (int db = 0; db < 4; ++db)
#pragma unroll
      for (int r = 0; r < 16; ++r) {
        const int q = qh * 32 + (r & 3) + 8 * (r >> 2) + 4 * hi;
        const float o2v = *(const float*)(smem + q * 512 + (db * 32 + ln) * 4);
        op[q * D_DIM + db * 32 + ln] = o[db][r] * wq[r] - o2v;
      }
  }
}

extern "C" void kernel_launch(void* const* d_in, const int* in_sizes, int n_in,
                              void* d_out, int out_size, void* d_ws, size_t ws_size,
                              hipStream_t stream) {
  const float* Q1 = (const float*)d_in[0];
  const float* Q2 = (const float*)d_in[1];
  const float* K1 = (const float*)d_in[2];
  const float* K2 = (const float*)d_in[3];
  const float* V  = (const float*)d_in[4];
  const float* lm = (const float*)d_in[5];
  float* O = (float*)d_out;

  unsigned short* wsp = (unsigned short*)d_ws;   // 24 MB

  prepass<<<dim3(B_DIM * NT), dim3(256), 0, stream>>>(K1, K2, V, wsp);
  diffattn<<<dim3(B_DIM * (KQ / QBLK)), dim3(256), 0, stream>>>(Q1, Q2, wsp, lm, O);
}